// Round 2
// 283.090 us; speedup vs baseline: 1.0012x; 1.0012x over previous
//
#include <hip/hip_runtime.h>

// MKGCN — R7b: resubmission of R7 (previous round hit an MI355X container
// acquisition failure, no kernel verdict). Latency-bound attack:
//  1) LDS diet 31.5KB -> 22.3KB (x1 merged into v1; r2T parked in attn buf;
//     b/v0/h0 in registers) -> 7 blocks/CU (28 waves, was 5/20).
//  2) All intra-wave barriers replaced by zero-cost compiler fences (pe[w] is
//     wave-private; DS is in-order per wave). ONE real __syncthreads()
//     remains (Wl staging is cross-wave) -> waves run the random-gather
//     phase decoupled instead of convoying.
//  3) #pragma unroll 8 in the hop-2 gather + __launch_bounds__(256,7)
//     (VGPR cap ~73) -> more gather loads in flight per wave.
// Matvec phases read the row via float4 LDS broadcast (40 vs 64 ops/row).

#define NT 256
#define WFENCE() asm volatile("" ::: "memory")

__device__ __forceinline__ float sigmoidf_(float x) { return 1.0f / (1.0f + __expf(-x)); }

__global__ __launch_bounds__(NT, 7) void mkgcn_wpe(
    const int* __restrict__ users,
    const int* __restrict__ items,
    const float* __restrict__ E,      // [1e6, 32]
    const float* __restrict__ R,      // [60, 32]
    const int* __restrict__ adjE,     // [1e6, 16]
    const int* __restrict__ adjR,     // [1e6, 16]
    const int* __restrict__ uhist,    // [1e5, 16]
    const float* __restrict__ Wg,     // [32, 32]
    const float* __restrict__ bg,     // [32]
    float* __restrict__ out,          // [B]
    int B)
{
    struct PE {
        int   e2[256];      // transposed: e2[k*16+n]
        float attn[256];    // r2T (ints) early -> attn[k*16+n] after P4
        float v1[16][32];   // v1 -> x1 (P5) -> hv1 (P6)
        float ue[32];
        float sdot[64];     // 60 used
        float attn0[16];
        float x0[32];       // x0 (P7) -> x0' (P9)
    };                      // 4672 B; pe[4]=18688 + Wl 4096 = 22784 -> 7 blocks/CU
    __shared__ __align__(16) float Wl[32][32];
    __shared__ __align__(16) PE pe[4];

    const int t = threadIdx.x;
    const int w = t >> 6;     // wave id
    const int L = t & 63;     // lane
    int b = blockIdx.x * 4 + w;
    if (b >= B) b = B - 1;    // tail clamp: duplicate compute, same value written
    PE& P = pe[w];

    const int user = users[b];
    const int item = items[b];

    // ---- P0: index rows (regs), v0 (regs), W, b (reg) ----
    int hid = 0, e1v = 0, r1v = 0;
    float v0r = 0.f;
    if (L < 16)       hid = uhist[(long)user * 16 + L];
    else if (L < 32)  e1v = adjE[(long)item * 16 + (L - 16)];
    else if (L < 48)  r1v = adjR[(long)item * 16 + (L - 32)];
    if (L < 32)       v0r = E[(long)item * 32 + L];
    ((float4*)Wl)[t] = ((const float4*)Wg)[t];
    const float bv = bg[L & 31];

    const int v  = L & 7;     // float4 index within row
    const int r8 = L >> 3;    // row group 0..7

    // ---- P1: history mean (register reduce), hop-2 adjacency (transposed), v1 ----
    {
        const int h0i = __shfl(hid, r8);
        const int h1i = __shfl(hid, r8 + 8);
        const float4 a = ((const float4*)(E + (long)h0i * 32))[v];
        const float4 c = ((const float4*)(E + (long)h1i * 32))[v];
        float sx = a.x + c.x, sy = a.y + c.y, sz = a.z + c.z, sw = a.w + c.w;
        #pragma unroll
        for (int off = 8; off < 64; off <<= 1) {
            sx += __shfl_xor(sx, off); sy += __shfl_xor(sy, off);
            sz += __shfl_xor(sz, off); sw += __shfl_xor(sw, off);
        }
        if (L < 8) {   // lane L has v == L here
            float4 u; u.x = sx * 0.0625f; u.y = sy * 0.0625f;
            u.z = sz * 0.0625f; u.w = sw * 0.0625f;
            ((float4*)P.ue)[L] = u;
        }
    }
    {
        const int n = L >> 2, c4 = L & 3;
        const int e1n = __shfl(e1v, 16 + n);
        const int4 ev = ((const int4*)(adjE + (long)e1n * 16))[c4];
        const int4 rv = ((const int4*)(adjR + (long)e1n * 16))[c4];
        int* r2Ti = (int*)P.attn;           // park r2T in attn buffer (dead until P4)
        P.e2[(c4 * 4 + 0) * 16 + n] = ev.x;  P.e2[(c4 * 4 + 1) * 16 + n] = ev.y;
        P.e2[(c4 * 4 + 2) * 16 + n] = ev.z;  P.e2[(c4 * 4 + 3) * 16 + n] = ev.w;
        r2Ti[(c4 * 4 + 0) * 16 + n] = rv.x;  r2Ti[(c4 * 4 + 1) * 16 + n] = rv.y;
        r2Ti[(c4 * 4 + 2) * 16 + n] = rv.z;  r2Ti[(c4 * 4 + 3) * 16 + n] = rv.w;
    }
    #pragma unroll
    for (int it = 0; it < 2; ++it) {
        const int r = r8 + 8 * it;
        const int e1r = __shfl(e1v, 16 + r);
        ((float4*)P.v1)[r * 8 + v] = ((const float4*)(E + (long)e1r * 32))[v];
    }
    WFENCE();   // ue, e2, r2T, v1 ready (wave-private)

    // ---- P3: sdot[r] = dot(ue, R[r]) ----
    if (L < 60) {
        const float4* rr = (const float4*)(R + L * 32);
        const float4* uu = (const float4*)P.ue;
        float s = 0.f;
        #pragma unroll
        for (int j = 0; j < 8; ++j) {
            const float4 a = rr[j], u = uu[j];
            s += a.x * u.x + a.y * u.y + a.z * u.z + a.w * u.w;
        }
        P.sdot[L] = s;
    }
    WFENCE();   // sdot ready

    // ---- P4: softmax attention, in place over r2T (each slot owned by one lane) ----
    {
        const int* r2T = (const int*)P.attn;
        #pragma unroll
        for (int c = 0; c < 4; ++c) {
            const int k = L & 15, n = c * 4 + (L >> 4);
            const float s = P.sdot[r2T[k * 16 + n]];
            float m = s;
            #pragma unroll
            for (int off = 1; off < 16; off <<= 1) m = fmaxf(m, __shfl_xor(m, off, 16));
            const float e = __expf(s - m);
            float sum = e;
            #pragma unroll
            for (int off = 1; off < 16; off <<= 1) sum += __shfl_xor(sum, off, 16);
            P.attn[k * 16 + n] = e / sum;
        }
    }
    const int r1L = __shfl(r1v, 32 + (L & 15));   // hoisted: sources lanes 32..47
    if (L < 16) {
        const float s = P.sdot[r1L];
        float m = s;
        #pragma unroll
        for (int off = 1; off < 16; off <<= 1) m = fmaxf(m, __shfl_xor(m, off, 16));
        const float e = __expf(s - m);
        float sum = e;
        #pragma unroll
        for (int off = 1; off < 16; off <<= 1) sum += __shfl_xor(sum, off, 16);
        P.attn0[L] = e / sum;
    }
    WFENCE();   // attn, attn0 ready; r2T dead

    // ---- P7 (hoisted): item aggregation over ORIGINAL v1, before P5 overwrites ----
    if (L < 32) {
        float a = 0.f;
        #pragma unroll
        for (int k = 0; k < 16; ++k) a += P.attn0[k] * P.v1[k][L];
        P.x0[L] = v0r + a;
    }
    WFENCE();   // all v1 reads ordered before P5's in-place writes

    // ---- P5: hop-2 weighted gather. x1 overwrites v1 (each f4 slot lane-owned) ----
    {
        const int n  = L >> 2;
        const int s0 = (L & 3) * 2;
        float ax0 = 0, ay0 = 0, az0 = 0, aw0 = 0;
        float ax1 = 0, ay1 = 0, az1 = 0, aw1 = 0;
        #pragma unroll 8
        for (int k = 0; k < 16; ++k) {
            const int   row = P.e2[k * 16 + n];     // conflict-free broadcast
            const float aw  = P.attn[k * 16 + n];
            const float4* er = (const float4*)(E + (long)row * 32);
            const float4 f0 = er[s0];
            const float4 f1 = er[s0 + 1];
            ax0 += aw * f0.x; ay0 += aw * f0.y; az0 += aw * f0.z; aw0 += aw * f0.w;
            ax1 += aw * f1.x; ay1 += aw * f1.y; az1 += aw * f1.z; aw1 += aw * f1.w;
        }
        const float4 va = ((const float4*)P.v1)[n * 8 + s0];
        const float4 vb = ((const float4*)P.v1)[n * 8 + s0 + 1];
        float4 xa, xb;
        xa.x = va.x + ax0; xa.y = va.y + ay0; xa.z = va.z + az0; xa.w = va.w + aw0;
        xb.x = vb.x + ax1; xb.y = vb.y + ay1; xb.z = vb.z + az1; xb.w = vb.w + aw1;
        ((float4*)P.v1)[n * 8 + s0]     = xa;
        ((float4*)P.v1)[n * 8 + s0 + 1] = xb;
    }

    __syncthreads();   // ONLY block barrier: Wl visibility (cross-wave); x1 complete

    // ---- P6: hop-1 matvec + sigmoid; hv1 overwrites x1 in place ----
    const int dp = L & 31, half = L >> 5;
    {
        float hv[8];
        #pragma unroll
        for (int p = 0; p < 8; ++p) {
            const int n = p * 2 + half;
            float acc = bv;
            const float4* xr = (const float4*)P.v1[n];   // broadcast reads
            #pragma unroll
            for (int d4 = 0; d4 < 8; ++d4) {
                const float4 xv = xr[d4];
                acc += xv.x * Wl[d4 * 4 + 0][dp];
                acc += xv.y * Wl[d4 * 4 + 1][dp];
                acc += xv.z * Wl[d4 * 4 + 2][dp];
                acc += xv.w * Wl[d4 * 4 + 3][dp];
            }
            hv[p] = sigmoidf_(acc);
        }
        WFENCE();      // all reads ordered before in-place writes
        #pragma unroll
        for (int p = 0; p < 8; ++p) P.v1[p * 2 + half][dp] = hv[p];
    }
    WFENCE();   // hv1 ready

    // ---- P8: item matvec + sigmoid; h0 stays in a register ----
    float h0r = 0.f;
    if (L < 32) {
        float acc = bv;
        const float4* xr = (const float4*)P.x0;
        #pragma unroll
        for (int d4 = 0; d4 < 8; ++d4) {
            const float4 xv = xr[d4];
            acc += xv.x * Wl[d4 * 4 + 0][L];
            acc += xv.y * Wl[d4 * 4 + 1][L];
            acc += xv.z * Wl[d4 * 4 + 2][L];
            acc += xv.w * Wl[d4 * 4 + 3][L];
        }
        h0r = sigmoidf_(acc);
    }
    WFENCE();   // x0 reads ordered before P9's in-place write

    // ---- P9: iteration-1 aggregation (same attn0) over hv1; x0' over x0 ----
    if (L < 32) {
        float a = 0.f;
        #pragma unroll
        for (int k = 0; k < 16; ++k) a += P.attn0[k] * P.v1[k][L];
        P.x0[L] = h0r + a;
    }
    WFENCE();   // x0' ready

    // ---- P10: final matvec + tanh, dot(ue), sigmoid ----
    if (L < 32) {
        float acc = bv;
        const float4* xr = (const float4*)P.x0;
        #pragma unroll
        for (int d4 = 0; d4 < 8; ++d4) {
            const float4 xv = xr[d4];
            acc += xv.x * Wl[d4 * 4 + 0][L];
            acc += xv.y * Wl[d4 * 4 + 1][L];
            acc += xv.z * Wl[d4 * 4 + 2][L];
            acc += xv.w * Wl[d4 * 4 + 3][L];
        }
        const float ie = tanhf(acc);
        float pr = P.ue[L] * ie;
        #pragma unroll
        for (int off = 1; off < 32; off <<= 1) pr += __shfl_xor(pr, off, 32);
        if (L == 0) out[b] = sigmoidf_(pr);
    }
}

extern "C" void kernel_launch(void* const* d_in, const int* in_sizes, int n_in,
                              void* d_out, int out_size, void* d_ws, size_t ws_size,
                              hipStream_t stream) {
    const int* users   = (const int*)d_in[0];
    const int* items   = (const int*)d_in[1];
    const float* E     = (const float*)d_in[2];
    const float* R     = (const float*)d_in[3];
    const int* adjE    = (const int*)d_in[4];
    const int* adjR    = (const int*)d_in[5];
    const int* uhist   = (const int*)d_in[6];
    const float* Wg    = (const float*)d_in[7];
    const float* bg    = (const float*)d_in[8];
    float* out         = (float*)d_out;

    const int B = in_sizes[0];
    const int grid = (B + 3) / 4;
    mkgcn_wpe<<<grid, NT, 0, stream>>>(users, items, E, R, adjE, adjR, uhist, Wg, bg, out, B);
}

// Round 3
// 281.490 us; speedup vs baseline: 1.0069x; 1.0057x over previous
//
#include <hip/hip_runtime.h>

// MKGCN — R8: force per-wave MLP in the hop-2 gather. R7's occupancy probe
// (39->62% waves, zero BW change) plus VGPR_Count=36 showed the compiler
// serialized the gather (ds_read idx -> addr -> load -> waitcnt -> fma per k).
// P5 is now explicitly chunked: per chunk of 4 k, batch LDS-read 4 idx + 4
// attn into regs, issue all 8 float4 global loads into a statically-indexed
// f[8] reg array, then FMA. launch_bounds(256,6) lifts VGPR cap to ~85 so the
// payload stays in flight (expected Q≈8 lines/wave vs ~4 before).
// Accumulation order per lane unchanged (k ascending) -> bit-identical.
// Everything else identical to R7 (passed, absmax 0).

#define NT 256
#define WFENCE() asm volatile("" ::: "memory")

__device__ __forceinline__ float sigmoidf_(float x) { return 1.0f / (1.0f + __expf(-x)); }

__global__ __launch_bounds__(NT, 6) void mkgcn_wpe(
    const int* __restrict__ users,
    const int* __restrict__ items,
    const float* __restrict__ E,      // [1e6, 32]
    const float* __restrict__ R,      // [60, 32]
    const int* __restrict__ adjE,     // [1e6, 16]
    const int* __restrict__ adjR,     // [1e6, 16]
    const int* __restrict__ uhist,    // [1e5, 16]
    const float* __restrict__ Wg,     // [32, 32]
    const float* __restrict__ bg,     // [32]
    float* __restrict__ out,          // [B]
    int B)
{
    struct PE {
        int   e2[256];      // transposed: e2[k*16+n]
        float attn[256];    // r2T (ints) early -> attn[k*16+n] after P4
        float v1[16][32];   // v1 -> x1 (P5) -> hv1 (P6)
        float ue[32];
        float sdot[64];     // 60 used
        float attn0[16];
        float x0[32];       // x0 (P7) -> x0' (P9)
    };                      // 4672 B; pe[4]=18688 + Wl 4096 = 22784 -> LDS 23040
    __shared__ __align__(16) float Wl[32][32];
    __shared__ __align__(16) PE pe[4];

    const int t = threadIdx.x;
    const int w = t >> 6;     // wave id
    const int L = t & 63;     // lane
    int b = blockIdx.x * 4 + w;
    if (b >= B) b = B - 1;    // tail clamp: duplicate compute, same value written
    PE& P = pe[w];

    const int user = users[b];
    const int item = items[b];

    // ---- P0: index rows (regs), v0 (regs), W, b (reg) ----
    int hid = 0, e1v = 0, r1v = 0;
    float v0r = 0.f;
    if (L < 16)       hid = uhist[(long)user * 16 + L];
    else if (L < 32)  e1v = adjE[(long)item * 16 + (L - 16)];
    else if (L < 48)  r1v = adjR[(long)item * 16 + (L - 32)];
    if (L < 32)       v0r = E[(long)item * 32 + L];
    ((float4*)Wl)[t] = ((const float4*)Wg)[t];
    const float bv = bg[L & 31];

    const int v  = L & 7;     // float4 index within row
    const int r8 = L >> 3;    // row group 0..7

    // ---- P1: history mean (register reduce), hop-2 adjacency (transposed), v1 ----
    {
        const int h0i = __shfl(hid, r8);
        const int h1i = __shfl(hid, r8 + 8);
        const float4 a = ((const float4*)(E + (long)h0i * 32))[v];
        const float4 c = ((const float4*)(E + (long)h1i * 32))[v];
        float sx = a.x + c.x, sy = a.y + c.y, sz = a.z + c.z, sw = a.w + c.w;
        #pragma unroll
        for (int off = 8; off < 64; off <<= 1) {
            sx += __shfl_xor(sx, off); sy += __shfl_xor(sy, off);
            sz += __shfl_xor(sz, off); sw += __shfl_xor(sw, off);
        }
        if (L < 8) {   // lane L has v == L here
            float4 u; u.x = sx * 0.0625f; u.y = sy * 0.0625f;
            u.z = sz * 0.0625f; u.w = sw * 0.0625f;
            ((float4*)P.ue)[L] = u;
        }
    }
    {
        const int n = L >> 2, c4 = L & 3;
        const int e1n = __shfl(e1v, 16 + n);
        const int4 ev = ((const int4*)(adjE + (long)e1n * 16))[c4];
        const int4 rv = ((const int4*)(adjR + (long)e1n * 16))[c4];
        int* r2Ti = (int*)P.attn;           // park r2T in attn buffer (dead until P4)
        P.e2[(c4 * 4 + 0) * 16 + n] = ev.x;  P.e2[(c4 * 4 + 1) * 16 + n] = ev.y;
        P.e2[(c4 * 4 + 2) * 16 + n] = ev.z;  P.e2[(c4 * 4 + 3) * 16 + n] = ev.w;
        r2Ti[(c4 * 4 + 0) * 16 + n] = rv.x;  r2Ti[(c4 * 4 + 1) * 16 + n] = rv.y;
        r2Ti[(c4 * 4 + 2) * 16 + n] = rv.z;  r2Ti[(c4 * 4 + 3) * 16 + n] = rv.w;
    }
    #pragma unroll
    for (int it = 0; it < 2; ++it) {
        const int r = r8 + 8 * it;
        const int e1r = __shfl(e1v, 16 + r);
        ((float4*)P.v1)[r * 8 + v] = ((const float4*)(E + (long)e1r * 32))[v];
    }
    WFENCE();   // ue, e2, r2T, v1 ready (wave-private)

    // ---- P3: sdot[r] = dot(ue, R[r]) ----
    if (L < 60) {
        const float4* rr = (const float4*)(R + L * 32);
        const float4* uu = (const float4*)P.ue;
        float s = 0.f;
        #pragma unroll
        for (int j = 0; j < 8; ++j) {
            const float4 a = rr[j], u = uu[j];
            s += a.x * u.x + a.y * u.y + a.z * u.z + a.w * u.w;
        }
        P.sdot[L] = s;
    }
    WFENCE();   // sdot ready

    // ---- P4: softmax attention, in place over r2T (each slot owned by one lane) ----
    {
        const int* r2T = (const int*)P.attn;
        #pragma unroll
        for (int c = 0; c < 4; ++c) {
            const int k = L & 15, n = c * 4 + (L >> 4);
            const float s = P.sdot[r2T[k * 16 + n]];
            float m = s;
            #pragma unroll
            for (int off = 1; off < 16; off <<= 1) m = fmaxf(m, __shfl_xor(m, off, 16));
            const float e = __expf(s - m);
            float sum = e;
            #pragma unroll
            for (int off = 1; off < 16; off <<= 1) sum += __shfl_xor(sum, off, 16);
            P.attn[k * 16 + n] = e / sum;
        }
    }
    const int r1L = __shfl(r1v, 32 + (L & 15));   // hoisted: sources lanes 32..47
    if (L < 16) {
        const float s = P.sdot[r1L];
        float m = s;
        #pragma unroll
        for (int off = 1; off < 16; off <<= 1) m = fmaxf(m, __shfl_xor(m, off, 16));
        const float e = __expf(s - m);
        float sum = e;
        #pragma unroll
        for (int off = 1; off < 16; off <<= 1) sum += __shfl_xor(sum, off, 16);
        P.attn0[L] = e / sum;
    }
    WFENCE();   // attn, attn0 ready; r2T dead

    // ---- P7 (hoisted): item aggregation over ORIGINAL v1, before P5 overwrites ----
    if (L < 32) {
        float a = 0.f;
        #pragma unroll
        for (int k = 0; k < 16; ++k) a += P.attn0[k] * P.v1[k][L];
        P.x0[L] = v0r + a;
    }
    WFENCE();   // all v1 reads ordered before P5's in-place writes

    // ---- P5: hop-2 weighted gather, explicit MLP chunks. x1 overwrites v1 ----
    {
        const int n  = L >> 2;
        const int s0 = (L & 3) * 2;
        float ax0 = 0, ay0 = 0, az0 = 0, aw0 = 0;
        float ax1 = 0, ay1 = 0, az1 = 0, aw1 = 0;
        #pragma unroll
        for (int kc = 0; kc < 4; ++kc) {
            // (a) batch LDS reads: 4 indices + 4 weights into regs
            int   rowi[4];
            float awt[4];
            #pragma unroll
            for (int j = 0; j < 4; ++j) {
                rowi[j] = P.e2[(kc * 4 + j) * 16 + n];     // conflict-free broadcast
                awt[j]  = P.attn[(kc * 4 + j) * 16 + n];
            }
            // (b) issue all 8 global float4 loads (statically-indexed regs)
            float4 f[8];
            #pragma unroll
            for (int j = 0; j < 4; ++j) {
                const float4* er = (const float4*)(E + (long)rowi[j] * 32);
                f[2 * j]     = er[s0];
                f[2 * j + 1] = er[s0 + 1];
            }
            // (c) consume, k ascending (same FMA order as before -> bit-identical)
            #pragma unroll
            for (int j = 0; j < 4; ++j) {
                const float aw = awt[j];
                ax0 += aw * f[2 * j].x;     ay0 += aw * f[2 * j].y;
                az0 += aw * f[2 * j].z;     aw0 += aw * f[2 * j].w;
                ax1 += aw * f[2 * j + 1].x; ay1 += aw * f[2 * j + 1].y;
                az1 += aw * f[2 * j + 1].z; aw1 += aw * f[2 * j + 1].w;
            }
        }
        const float4 va = ((const float4*)P.v1)[n * 8 + s0];
        const float4 vb = ((const float4*)P.v1)[n * 8 + s0 + 1];
        float4 xa, xb;
        xa.x = va.x + ax0; xa.y = va.y + ay0; xa.z = va.z + az0; xa.w = va.w + aw0;
        xb.x = vb.x + ax1; xb.y = vb.y + ay1; xb.z = vb.z + az1; xb.w = vb.w + aw1;
        ((float4*)P.v1)[n * 8 + s0]     = xa;
        ((float4*)P.v1)[n * 8 + s0 + 1] = xb;
    }

    __syncthreads();   // ONLY block barrier: Wl visibility (cross-wave); x1 complete

    // ---- P6: hop-1 matvec + sigmoid; hv1 overwrites x1 in place ----
    const int dp = L & 31, half = L >> 5;
    {
        float hv[8];
        #pragma unroll
        for (int p = 0; p < 8; ++p) {
            const int n = p * 2 + half;
            float acc = bv;
            const float4* xr = (const float4*)P.v1[n];   // broadcast reads
            #pragma unroll
            for (int d4 = 0; d4 < 8; ++d4) {
                const float4 xv = xr[d4];
                acc += xv.x * Wl[d4 * 4 + 0][dp];
                acc += xv.y * Wl[d4 * 4 + 1][dp];
                acc += xv.z * Wl[d4 * 4 + 2][dp];
                acc += xv.w * Wl[d4 * 4 + 3][dp];
            }
            hv[p] = sigmoidf_(acc);
        }
        WFENCE();      // all reads ordered before in-place writes
        #pragma unroll
        for (int p = 0; p < 8; ++p) P.v1[p * 2 + half][dp] = hv[p];
    }
    WFENCE();   // hv1 ready

    // ---- P8: item matvec + sigmoid; h0 stays in a register ----
    float h0r = 0.f;
    if (L < 32) {
        float acc = bv;
        const float4* xr = (const float4*)P.x0;
        #pragma unroll
        for (int d4 = 0; d4 < 8; ++d4) {
            const float4 xv = xr[d4];
            acc += xv.x * Wl[d4 * 4 + 0][L];
            acc += xv.y * Wl[d4 * 4 + 1][L];
            acc += xv.z * Wl[d4 * 4 + 2][L];
            acc += xv.w * Wl[d4 * 4 + 3][L];
        }
        h0r = sigmoidf_(acc);
    }
    WFENCE();   // x0 reads ordered before P9's in-place write

    // ---- P9: iteration-1 aggregation (same attn0) over hv1; x0' over x0 ----
    if (L < 32) {
        float a = 0.f;
        #pragma unroll
        for (int k = 0; k < 16; ++k) a += P.attn0[k] * P.v1[k][L];
        P.x0[L] = h0r + a;
    }
    WFENCE();   // x0' ready

    // ---- P10: final matvec + tanh, dot(ue), sigmoid ----
    if (L < 32) {
        float acc = bv;
        const float4* xr = (const float4*)P.x0;
        #pragma unroll
        for (int d4 = 0; d4 < 8; ++d4) {
            const float4 xv = xr[d4];
            acc += xv.x * Wl[d4 * 4 + 0][L];
            acc += xv.y * Wl[d4 * 4 + 1][L];
            acc += xv.z * Wl[d4 * 4 + 2][L];
            acc += xv.w * Wl[d4 * 4 + 3][L];
        }
        const float ie = tanhf(acc);
        float pr = P.ue[L] * ie;
        #pragma unroll
        for (int off = 1; off < 32; off <<= 1) pr += __shfl_xor(pr, off, 32);
        if (L == 0) out[b] = sigmoidf_(pr);
    }
}

extern "C" void kernel_launch(void* const* d_in, const int* in_sizes, int n_in,
                              void* d_out, int out_size, void* d_ws, size_t ws_size,
                              hipStream_t stream) {
    const int* users   = (const int*)d_in[0];
    const int* items   = (const int*)d_in[1];
    const float* E     = (const float*)d_in[2];
    const float* R     = (const float*)d_in[3];
    const int* adjE    = (const int*)d_in[4];
    const int* adjR    = (const int*)d_in[5];
    const int* uhist   = (const int*)d_in[6];
    const float* Wg    = (const float*)d_in[7];
    const float* bg    = (const float*)d_in[8];
    float* out         = (float*)d_out;

    const int B = in_sizes[0];
    const int grid = (B + 3) / 4;
    mkgcn_wpe<<<grid, NT, 0, stream>>>(users, items, E, R, adjE, adjR, uhist, Wg, bg, out, B);
}